// Round 13
// baseline (163.625 us; speedup 1.0000x reference)
//
#include <hip/hip_runtime.h>
#include <hip/hip_bf16.h>

#define DH 32
#define BSZ 128      // nodes per bucket (v_local = 7 bits)
#define NBP 1024     // padded bucket count (N <= 131072 => B <= 1024)
#define SCAT_E 3840  // edges per scatter block
#define SCAT_P (2 * SCAT_E)
#define EPT 15       // edges per thread in scatter (SCAT_E/256)
#define PRE_E 8192   // edges per precount block
#define CPG 16       // channels per sub-block in bucket_max
#define TS 4096      // pair codes per LDS tile in bucket_max
#define PAD 17       // aggL words per node (16 channels + 1 pad)

// ---------------------------------------------------------------------------
// Exclusive scan of gtotal[0..NBP) -> gbase; gcursor = gbase. One block.
// ---------------------------------------------------------------------------
__global__ __launch_bounds__(256) void scan_buckets(
    const int* __restrict__ gtotal, int* __restrict__ gbase,
    int* __restrict__ gcursor)
{
    __shared__ int ss[256];
    const int t = threadIdx.x;
    int v0 = gtotal[4 * t], v1 = gtotal[4 * t + 1];
    int v2 = gtotal[4 * t + 2], v3 = gtotal[4 * t + 3];
    int tsum = v0 + v1 + v2 + v3;
    ss[t] = tsum;
    __syncthreads();
    for (int off = 1; off < 256; off <<= 1) {
        int y = (t >= off) ? ss[t - off] : 0;
        __syncthreads();
        ss[t] += y;
        __syncthreads();
    }
    int e = ss[t] - tsum;
    gbase[4 * t] = e;                    gcursor[4 * t] = e;
    gbase[4 * t + 1] = e + v0;           gcursor[4 * t + 1] = e + v0;
    gbase[4 * t + 2] = e + v0 + v1;      gcursor[4 * t + 2] = e + v0 + v1;
    gbase[4 * t + 3] = e + v0 + v1 + v2; gcursor[4 * t + 3] = e + v0 + v1 + v2;
}

// ---------------------------------------------------------------------------
// FUSED: blocks [0,pgrid) = precount; blocks [pgrid,...) = node projection,
// 2 NODES x 16 CHANNELS per thread (half = tid&1, pair = tid>>1):
//  - weight b128 broadcast feeds 8 FMAs (sharing kept at 2 nodes/read)
//  - 100K threads -> ~6 waves/CU (vs 3 with 2-node full-channel)
//  - GEMM2/Wf get the partner half's h via __shfl_xor(.,1) (same wave,
//    pair-uniform exit -> partners never diverge)
// ---------------------------------------------------------------------------
union PreProjSmem {
    int hist[NBP];                      // 4 KB (precount path)
    struct {                            // ~25 KB (proj path)
        float W1[128 * 32];             // [k][c]
        float W2[32 * 32];
        float Wf[32 * 32];              // W_ffnn rows 0..31
        float b1[32], b2[32], bf[32];
    } pj;
};

__global__ __launch_bounds__(256) void precount_proj(
    const int* __restrict__ src, const int* __restrict__ dst,
    int* __restrict__ gtotal, int E, int pgrid,
    const float* __restrict__ feat,
    const float* __restrict__ W_in, const float* __restrict__ b_in,
    const float* __restrict__ W_nbr, const float* __restrict__ b_nbr,
    const float* __restrict__ b_n1,
    const float* __restrict__ W_ffnn, const float* __restrict__ b_ffnn,
    float* __restrict__ hpart, unsigned* __restrict__ ub32, int N)
{
    __shared__ PreProjSmem sm;
    const int tid = threadIdx.x;

    if ((int)blockIdx.x < pgrid) {
        // ================= precount path =================
        for (int i = tid; i < NBP; i += 256) sm.hist[i] = 0;
        __syncthreads();
        const int e0 = blockIdx.x * PRE_E;
        const int eend = min(e0 + PRE_E, E);
        for (int e = e0 + tid; e < eend; e += 256) {
            atomicAdd(&sm.hist[src[e] >> 7], 1);
            atomicAdd(&sm.hist[dst[e] >> 7], 1);
        }
        __syncthreads();
        for (int i = tid; i < NBP; i += 256)
            if (sm.hist[i] > 0) atomicAdd(&gtotal[i], sm.hist[i]);
        return;
    }

    // ================= proj path (2 nodes x 16 channels / thread) ==========
    for (int i = tid; i < 128 * 32; i += 256) sm.pj.W1[i] = W_in[i];
    for (int i = tid; i < 32 * 32; i += 256) sm.pj.W2[i] = W_nbr[i];
    for (int i = tid; i < 32 * 32; i += 256) sm.pj.Wf[i] = W_ffnn[i];
    if (tid < 32) {
        sm.pj.b1[tid] = b_in[tid];
        sm.pj.b2[tid] = b_nbr[tid] + b_n1[tid];
        sm.pj.bf[tid] = b_ffnn[tid];
    }
    __syncthreads();

    const int half = tid & 1;
    const int pair = ((int)blockIdx.x - pgrid) * 128 + (tid >> 1);
    const int n0 = 2 * pair;
    if (n0 >= N) return;                 // pair-uniform: both lanes exit
    const int n1 = n0 + 1;
    const bool v1 = (n1 < N);
    const int n1c = v1 ? n1 : n0;
    const int co = half * 16;            // channel offset

    const float4* f0 = (const float4*)(feat + (size_t)n0 * 128);
    const float4* f1 = (const float4*)(feat + (size_t)n1c * 128);

    float a0[16], a1[16];
#pragma unroll
    for (int c = 0; c < 16; ++c) { a0[c] = sm.pj.b1[co + c]; a1[c] = a0[c]; }

    // GEMM1: one broadcast w b128 feeds 2 nodes x 4 channels
#pragma unroll 2
    for (int k4 = 0; k4 < 32; ++k4) {
        const float4 x0 = f0[k4];
        const float4 x1 = f1[k4];
#pragma unroll
        for (int kk = 0; kk < 4; ++kk) {
            const float fk0 = (kk == 0) ? x0.x : (kk == 1) ? x0.y : (kk == 2) ? x0.z : x0.w;
            const float fk1 = (kk == 0) ? x1.x : (kk == 1) ? x1.y : (kk == 2) ? x1.z : x1.w;
            const float4* wr = (const float4*)&sm.pj.W1[(k4 * 4 + kk) * 32 + co];
#pragma unroll
            for (int c4 = 0; c4 < 4; ++c4) {
                float4 w = wr[c4];
                a0[c4 * 4 + 0] = fmaf(fk0, w.x, a0[c4 * 4 + 0]);
                a0[c4 * 4 + 1] = fmaf(fk0, w.y, a0[c4 * 4 + 1]);
                a0[c4 * 4 + 2] = fmaf(fk0, w.z, a0[c4 * 4 + 2]);
                a0[c4 * 4 + 3] = fmaf(fk0, w.w, a0[c4 * 4 + 3]);
                a1[c4 * 4 + 0] = fmaf(fk1, w.x, a1[c4 * 4 + 0]);
                a1[c4 * 4 + 1] = fmaf(fk1, w.y, a1[c4 * 4 + 1]);
                a1[c4 * 4 + 2] = fmaf(fk1, w.z, a1[c4 * 4 + 2]);
                a1[c4 * 4 + 3] = fmaf(fk1, w.w, a1[c4 * 4 + 3]);
            }
        }
    }

    // GEMM2: u = sigmoid(h @ W2 + b2); partner half via shfl_xor(.,1)
    {
        float u0[16], u1[16];
#pragma unroll
        for (int c = 0; c < 16; ++c) { u0[c] = sm.pj.b2[co + c]; u1[c] = u0[c]; }
#pragma unroll
        for (int k = 0; k < 32; ++k) {
            float s0 = a0[k & 15], s1 = a1[k & 15];
            float t0 = __shfl_xor(s0, 1, 64), t1 = __shfl_xor(s1, 1, 64);
            float h0 = ((k >> 4) == half) ? s0 : t0;
            float h1 = ((k >> 4) == half) ? s1 : t1;
            const float4* wr = (const float4*)&sm.pj.W2[k * 32 + co];
#pragma unroll
            for (int c4 = 0; c4 < 4; ++c4) {
                float4 w = wr[c4];
                u0[c4 * 4 + 0] = fmaf(h0, w.x, u0[c4 * 4 + 0]);
                u0[c4 * 4 + 1] = fmaf(h0, w.y, u0[c4 * 4 + 1]);
                u0[c4 * 4 + 2] = fmaf(h0, w.z, u0[c4 * 4 + 2]);
                u0[c4 * 4 + 3] = fmaf(h0, w.w, u0[c4 * 4 + 3]);
                u1[c4 * 4 + 0] = fmaf(h1, w.x, u1[c4 * 4 + 0]);
                u1[c4 * 4 + 1] = fmaf(h1, w.y, u1[c4 * 4 + 1]);
                u1[c4 * 4 + 2] = fmaf(h1, w.z, u1[c4 * 4 + 2]);
                u1[c4 * 4 + 3] = fmaf(h1, w.w, u1[c4 * 4 + 3]);
            }
        }
        // sigmoid -> bf16 (RNE); this thread's 16 ch = table `half`, 8 u32/node
#pragma unroll
        for (int j = 0; j < 8; ++j) {
            float s0 = 1.0f / (1.0f + __expf(-u0[2 * j]));
            float s1 = 1.0f / (1.0f + __expf(-u0[2 * j + 1]));
            unsigned b0 = __float_as_uint(s0);
            b0 += 0x7FFFu + ((b0 >> 16) & 1u);
            unsigned b1 = __float_as_uint(s1);
            b1 += 0x7FFFu + ((b1 >> 16) & 1u);
            ub32[((size_t)half * N + n0) * 8 + j] = (b0 >> 16) | (b1 & 0xFFFF0000u);
        }
        if (v1) {
#pragma unroll
            for (int j = 0; j < 8; ++j) {
                float s0 = 1.0f / (1.0f + __expf(-u1[2 * j]));
                float s1 = 1.0f / (1.0f + __expf(-u1[2 * j + 1]));
                unsigned b0 = __float_as_uint(s0);
                b0 += 0x7FFFu + ((b0 >> 16) & 1u);
                unsigned b1 = __float_as_uint(s1);
                b1 += 0x7FFFu + ((b1 >> 16) & 1u);
                ub32[((size_t)half * N + n1) * 8 + j] = (b0 >> 16) | (b1 & 0xFFFF0000u);
            }
        }
    }

    // hpart = h @ W_ffnn[0:32] + b_ffnn (same shfl pattern)
    {
        float g0[16], g1[16];
#pragma unroll
        for (int c = 0; c < 16; ++c) { g0[c] = sm.pj.bf[co + c]; g1[c] = g0[c]; }
#pragma unroll
        for (int k = 0; k < 32; ++k) {
            float s0 = a0[k & 15], s1 = a1[k & 15];
            float t0 = __shfl_xor(s0, 1, 64), t1 = __shfl_xor(s1, 1, 64);
            float h0 = ((k >> 4) == half) ? s0 : t0;
            float h1 = ((k >> 4) == half) ? s1 : t1;
            const float4* wr = (const float4*)&sm.pj.Wf[k * 32 + co];
#pragma unroll
            for (int c4 = 0; c4 < 4; ++c4) {
                float4 w = wr[c4];
                g0[c4 * 4 + 0] = fmaf(h0, w.x, g0[c4 * 4 + 0]);
                g0[c4 * 4 + 1] = fmaf(h0, w.y, g0[c4 * 4 + 1]);
                g0[c4 * 4 + 2] = fmaf(h0, w.z, g0[c4 * 4 + 2]);
                g0[c4 * 4 + 3] = fmaf(h0, w.w, g0[c4 * 4 + 3]);
                g1[c4 * 4 + 0] = fmaf(h1, w.x, g1[c4 * 4 + 0]);
                g1[c4 * 4 + 1] = fmaf(h1, w.y, g1[c4 * 4 + 1]);
                g1[c4 * 4 + 2] = fmaf(h1, w.z, g1[c4 * 4 + 2]);
                g1[c4 * 4 + 3] = fmaf(h1, w.w, g1[c4 * 4 + 3]);
            }
        }
        float4* h0r = (float4*)(hpart + (size_t)n0 * 32 + co);
#pragma unroll
        for (int c4 = 0; c4 < 4; ++c4)
            h0r[c4] = make_float4(g0[c4 * 4 + 0], g0[c4 * 4 + 1],
                                  g0[c4 * 4 + 2], g0[c4 * 4 + 3]);
        if (v1) {
            float4* h1r = (float4*)(hpart + (size_t)n1 * 32 + co);
#pragma unroll
            for (int c4 = 0; c4 < 4; ++c4)
                h1r[c4] = make_float4(g1[c4 * 4 + 0], g1[c4 * 4 + 1],
                                      g1[c4 * 4 + 2], g1[c4 * 4 + 3]);
        }
    }
}

// ---------------------------------------------------------------------------
// Bucket-granular scatter (standalone; 38.9 KB LDS, 4 blocks/CU).
// Bucket low byte rides in code bits 24..31; recovered via cur containment.
// ---------------------------------------------------------------------------
__global__ __launch_bounds__(256) void bucket_scatter(
    const int* __restrict__ src, const int* __restrict__ dst,
    int* __restrict__ gcursor, unsigned* __restrict__ pairs_g,
    int E, int B)
{
    __shared__ unsigned s_code[SCAT_P];     // 30 KB
    __shared__ int s_cur[NBP];              // 4 KB (counts -> starts -> ends)
    __shared__ int s_gbL[NBP];              // 4 KB (also scan temp [0..3])

    const int tid = threadIdx.x;
    const int e0 = blockIdx.x * SCAT_E;
    const int eend = min(e0 + SCAT_E, E);
    const int np = 2 * (eend - e0);

    for (int i = tid; i < NBP; i += 256) s_cur[i] = 0;
    __syncthreads();

    int es[EPT], dr[EPT];
#pragma unroll
    for (int j = 0; j < EPT; ++j) {
        int e = e0 + tid + j * 256;
        bool ok = (e < eend);
        es[j] = ok ? src[e] : -1;
        dr[j] = ok ? dst[e] : -1;
    }
#pragma unroll
    for (int j = 0; j < EPT; ++j) {
        if (es[j] >= 0) {
            atomicAdd(&s_cur[es[j] >> 7], 1);
            atomicAdd(&s_cur[dr[j] >> 7], 1);
        }
    }
    __syncthreads();

    // in-place exclusive scan of cur (counts -> starts); shfl-based
    {
        const int lane = tid & 63;
        const int w = tid >> 6;
        int v0 = s_cur[4 * tid], v1 = s_cur[4 * tid + 1];
        int v2 = s_cur[4 * tid + 2], v3 = s_cur[4 * tid + 3];
        int tsum = v0 + v1 + v2 + v3;
        int x = tsum;
#pragma unroll
        for (int off = 1; off < 64; off <<= 1) {
            int y = __shfl_up(x, off, 64);
            x += (lane >= off) ? y : 0;
        }
        if (lane == 63) s_gbL[w] = x;       // wave totals (temp use)
        __syncthreads();
        int woff = 0;
#pragma unroll
        for (int k = 0; k < 4; ++k) woff += (k < w) ? s_gbL[k] : 0;
        int ebase = woff + x - tsum;
        __syncthreads();                    // all reads of cur done
        s_cur[4 * tid] = ebase;
        s_cur[4 * tid + 1] = ebase + v0;
        s_cur[4 * tid + 2] = ebase + v0 + v1;
        s_cur[4 * tid + 3] = ebase + v0 + v1 + v2;
    }
    __syncthreads();

    // rank + reorder into LDS; bucket low byte in code[31:24]
#pragma unroll
    for (int j = 0; j < EPT; ++j) {
        if (es[j] >= 0) {
            int s = es[j], d = dr[j];
            int bs = s >> 7, bd = d >> 7;
            unsigned cs = ((unsigned)(bs & 255) << 24) |
                          ((unsigned)(s & 127) << 17) | (unsigned)d;
            unsigned cd = ((unsigned)(bd & 255) << 24) |
                          ((unsigned)(d & 127) << 17) | (unsigned)s;
            int p1 = atomicAdd(&s_cur[bs], 1);
            s_code[p1] = cs;
            int p2 = atomicAdd(&s_cur[bd], 1);
            s_code[p2] = cd;
        }
    }
    __syncthreads();
    // cur[b] = segment END; start(b) = cur[b-1] (segments packed)

    for (int b = tid; b < B; b += 256) {
        int end = s_cur[b];
        int start = b ? s_cur[b - 1] : 0;
        int c = end - start;
        if (c > 0) {
            int gw = atomicAdd(&gcursor[b], c);
            s_gbL[b] = gw - start;
        }
    }
    __syncthreads();

    // coalesced run writes; recover bucket via low byte + containment
    for (int i = tid; i < np; i += 256) {
        unsigned code = s_code[i];
        int cc = (int)(code >> 24);
#pragma unroll
        for (int k = 0; k < 3; ++k) {
            int hi2 = s_cur[cc];
            int lo2 = cc ? s_cur[cc - 1] : 0;
            bool in = (i < hi2) && (i >= lo2);
            cc = in ? cc : cc + 256;
        }
        pairs_g[s_gbL[cc] + i] = code & 0x00FFFFFFu;
    }
}

// ---------------------------------------------------------------------------
// Per-bucket segment max in LDS. XCD-aware decode: q = xcd>=4 so each XCD's
// L2 caches only ITS 3.2MB u-table. 16-deep unrolled gathers per lane.
// ---------------------------------------------------------------------------
__global__ __launch_bounds__(256) void bucket_max(
    const unsigned* __restrict__ pairs_g, const int* __restrict__ gbase,
    const int* __restrict__ gtotal, const unsigned* __restrict__ ub32,
    float* __restrict__ agg, int N, int B)
{
    __shared__ unsigned aggL[BSZ * PAD];   // 8.7 KB
    __shared__ int degL[BSZ];              // 0.5 KB
    __shared__ unsigned tile[TS];          // 16 KB

    const int tid = threadIdx.x;
    const int bid = blockIdx.x;
    const int xcd = bid & 7;
    const int q = xcd >> 2;                          // channel half by XCD group
    const int b = (bid >> 3) * 4 + (xcd & 3);
    if (b >= B) return;
    const int v0 = b * BSZ;
    const unsigned* ut = ub32 + (size_t)q * N * 8;   // 8 u32 per node

    for (int i = tid; i < BSZ * PAD; i += 256) aggL[i] = 0u;
    for (int i = tid; i < BSZ; i += 256) degL[i] = 0;
    __syncthreads();

    const int start = gbase[b];
    const int cnt = gtotal[b];
    const int gg = tid >> 3;       // 32 groups of 8 lanes
    const int cl = tid & 7;

    for (int t0 = 0; t0 < cnt; t0 += TS) {
        const int tn = min(TS, cnt - t0);
        for (int i = tid; i < tn; i += 256) tile[i] = pairs_g[start + t0 + i];
        __syncthreads();

        const int kmax = (tn - gg + 31) >> 5;   // <=0 if gg >= tn
        const int pm = tn - 1;
        for (int kk = 0; kk < kmax; kk += 16) {
            unsigned cc[16], xx[16];
#pragma unroll
            for (int u = 0; u < 16; ++u)
                cc[u] = tile[min(gg + (kk + u) * 32, pm)];
#pragma unroll
            for (int u = 0; u < 16; ++u)
                xx[u] = ut[(size_t)(cc[u] & 0x1FFFF) * 8 + cl];
#pragma unroll
            for (int u = 0; u < 16; ++u) {
                atomicMax(&aggL[(cc[u] >> 17) * PAD + 2 * cl], (xx[u] & 0xFFFFu) << 16);
                atomicMax(&aggL[(cc[u] >> 17) * PAD + 2 * cl + 1], xx[u] & 0xFFFF0000u);
            }
            if (cl == 0) {
#pragma unroll
                for (int u = 0; u < 16; ++u)
                    if (gg + (kk + u) * 32 < tn) atomicAdd(&degL[cc[u] >> 17], 1);
            }
        }
        __syncthreads();
    }

    for (int i = tid; i < BSZ * CPG; i += 256) {
        int vl = i >> 4;
        int v = v0 + vl;
        if (v < N) {
            float val = (degL[vl] > 1) ? __uint_as_float(aggL[vl * PAD + (i & 15)]) : 0.f;
            agg[(size_t)v * DH + q * CPG + (i & 15)] = val;
        }
    }
}

// ---------------------------------------------------------------------------
// out = hpart + agg @ W_ffnn[32:64]   (one thread per node)
// ---------------------------------------------------------------------------
__global__ __launch_bounds__(256) void fin(
    const float* __restrict__ hpart, const float* __restrict__ agg,
    const float* __restrict__ W_ffnn, float* __restrict__ out, int N)
{
    __shared__ float sW[32 * 32];   // bottom 32 rows, [k][c], 4 KB

    const int tid = threadIdx.x;
    for (int i = tid; i < 32 * 32; i += 256) sW[i] = W_ffnn[1024 + i];
    __syncthreads();

    const int node = blockIdx.x * 256 + tid;
    if (node >= N) return;

    const float4* hr = (const float4*)(hpart + (size_t)node * 32);
    const float4* ar = (const float4*)(agg + (size_t)node * 32);

    float acc[32];
#pragma unroll
    for (int c4 = 0; c4 < 8; ++c4) {
        float4 v = hr[c4];
        acc[c4 * 4 + 0] = v.x; acc[c4 * 4 + 1] = v.y;
        acc[c4 * 4 + 2] = v.z; acc[c4 * 4 + 3] = v.w;
    }

#pragma unroll 2
    for (int k4 = 0; k4 < 8; ++k4) {
        const float4 f = ar[k4];
        const float4* w0 = (const float4*)&sW[(k4 * 4 + 0) * 32];
        const float4* w1 = (const float4*)&sW[(k4 * 4 + 1) * 32];
        const float4* w2 = (const float4*)&sW[(k4 * 4 + 2) * 32];
        const float4* w3 = (const float4*)&sW[(k4 * 4 + 3) * 32];
#pragma unroll
        for (int c4 = 0; c4 < 8; ++c4) {
            float4 a0 = w0[c4], a1 = w1[c4], a2 = w2[c4], a3 = w3[c4];
            acc[c4 * 4 + 0] = fmaf(f.w, a3.x, fmaf(f.z, a2.x, fmaf(f.y, a1.x, fmaf(f.x, a0.x, acc[c4 * 4 + 0]))));
            acc[c4 * 4 + 1] = fmaf(f.w, a3.y, fmaf(f.z, a2.y, fmaf(f.y, a1.y, fmaf(f.x, a0.y, acc[c4 * 4 + 1]))));
            acc[c4 * 4 + 2] = fmaf(f.w, a3.z, fmaf(f.z, a2.z, fmaf(f.y, a1.z, fmaf(f.x, a0.z, acc[c4 * 4 + 2]))));
            acc[c4 * 4 + 3] = fmaf(f.w, a3.w, fmaf(f.z, a2.w, fmaf(f.y, a1.w, fmaf(f.x, a0.w, acc[c4 * 4 + 3]))));
        }
    }

    float4* orow = (float4*)(out + (size_t)node * 32);
#pragma unroll
    for (int c4 = 0; c4 < 8; ++c4)
        orow[c4] = make_float4(acc[c4 * 4 + 0], acc[c4 * 4 + 1],
                               acc[c4 * 4 + 2], acc[c4 * 4 + 3]);
}

// ---------------------------------------------------------------------------
extern "C" void kernel_launch(void* const* d_in, const int* in_sizes, int n_in,
                              void* d_out, int out_size, void* d_ws, size_t ws_size,
                              hipStream_t stream)
{
    const float* feat   = (const float*)d_in[0];
    const int*   src    = (const int*)d_in[1];
    const int*   dst    = (const int*)d_in[2];
    const float* W_in   = (const float*)d_in[3];
    const float* b_in   = (const float*)d_in[4];
    const float* W_nbr  = (const float*)d_in[5];
    const float* b_nbr  = (const float*)d_in[6];
    const float* b_n1   = (const float*)d_in[7];
    const float* W_ffnn = (const float*)d_in[8];
    const float* b_ffnn = (const float*)d_in[9];
    float* out = (float*)d_out;

    const int N = in_sizes[0] / 128;   // 100000 (N <= 131072 required by packing)
    const int E = in_sizes[1];
    const int B = (N + BSZ - 1) / BSZ; // 782 buckets (<= NBP)

    // u (bf16, channel-split, 6.4MB) aliases d_out (12.8MB): written by the
    // proj path, consumed by bucket_max, then fin overwrites out.
    unsigned* ub32 = (unsigned*)out;
    float* hpart   = (float*)d_ws;                    // N*32 f32
    float* agg     = hpart + (size_t)N * DH;          // N*32 f32
    int*   gtotal  = (int*)(agg + (size_t)N * DH);    // NBP
    int*   gbase   = gtotal + NBP;                    // NBP
    int*   gcursor = gbase + NBP;                     // NBP
    unsigned* pairs_g = (unsigned*)(gcursor + NBP);   // 2E u32

    const int egrid = (E + SCAT_E - 1) / SCAT_E;      // 261
    const int pgrid = (E + PRE_E - 1) / PRE_E;        // 123
    const int jgrid = (N + 255) / 256;                // 391 proj blocks (256 nodes each)
    const int npb = (N + 255) / 256;                  // 391

    hipMemsetAsync(gtotal, 0, NBP * sizeof(int), stream);
    precount_proj<<<pgrid + jgrid, 256, 0, stream>>>(
        src, dst, gtotal, E, pgrid,
        feat, W_in, b_in, W_nbr, b_nbr, b_n1, W_ffnn, b_ffnn,
        hpart, ub32, N);
    scan_buckets<<<1, 256, 0, stream>>>(gtotal, gbase, gcursor);
    bucket_scatter<<<egrid, 256, 0, stream>>>(src, dst, gcursor, pairs_g, E, B);
    bucket_max<<<((B + 3) / 4) * 8, 256, 0, stream>>>(
        pairs_g, gbase, gtotal, ub32, agg, N, B);
    fin<<<npb, 256, 0, stream>>>(hpart, agg, W_ffnn, out, N);
}

// Round 14
// 132.432 us; speedup vs baseline: 1.2355x; 1.2355x over previous
//
#include <hip/hip_runtime.h>
#include <hip/hip_bf16.h>

#define DH 32
#define BSZ 128      // nodes per bucket (v_local = 7 bits)
#define NBP 1024     // padded bucket count (N <= 131072 => B <= 1024)
#define SCAT_E 3840  // edges per scatter block
#define SCAT_P (2 * SCAT_E)
#define EPT 15       // edges per thread in scatter (SCAT_E/256)
#define PRE_E 8192   // edges per precount block
#define CPG 16       // channels per sub-block in bucket_max
#define TS 4096      // pair codes per LDS tile in bucket_max
#define PAD 17       // aggL words per node (16 channels + 1 pad)

// ---------------------------------------------------------------------------
// Exclusive scan of gtotal[0..NBP) -> gbase; gcursor = gbase. One block.
// ---------------------------------------------------------------------------
__global__ __launch_bounds__(256) void scan_buckets(
    const int* __restrict__ gtotal, int* __restrict__ gbase,
    int* __restrict__ gcursor)
{
    __shared__ int ss[256];
    const int t = threadIdx.x;
    int v0 = gtotal[4 * t], v1 = gtotal[4 * t + 1];
    int v2 = gtotal[4 * t + 2], v3 = gtotal[4 * t + 3];
    int tsum = v0 + v1 + v2 + v3;
    ss[t] = tsum;
    __syncthreads();
    for (int off = 1; off < 256; off <<= 1) {
        int y = (t >= off) ? ss[t - off] : 0;
        __syncthreads();
        ss[t] += y;
        __syncthreads();
    }
    int e = ss[t] - tsum;
    gbase[4 * t] = e;                    gcursor[4 * t] = e;
    gbase[4 * t + 1] = e + v0;           gcursor[4 * t + 1] = e + v0;
    gbase[4 * t + 2] = e + v0 + v1;      gcursor[4 * t + 2] = e + v0 + v1;
    gbase[4 * t + 3] = e + v0 + v1 + v2; gcursor[4 * t + 3] = e + v0 + v1 + v2;
}

// ---------------------------------------------------------------------------
// FUSED: blocks [0, jgrid) = node projection (1 node/thread, NO LDS —
// weights are wave-uniform scalar loads feeding v_fma SGPR operands);
// blocks [jgrid, jgrid+pgrid) = precount histogram.
//   h = feat @ W_in + b_in            (registers only)
//   u = sigmoid(h @ W_nbr + b2) -> bf16 channel-split tables
//   hpart = h @ W_ffnn[0:32] + b_ffnn
// ---------------------------------------------------------------------------
__global__ __launch_bounds__(256) void precount_proj(
    const int* __restrict__ src, const int* __restrict__ dst,
    int* __restrict__ gtotal, int E, int jgrid,
    const float* __restrict__ feat,
    const float* __restrict__ W_in, const float* __restrict__ b_in,
    const float* __restrict__ W_nbr, const float* __restrict__ b_nbr,
    const float* __restrict__ b_n1,
    const float* __restrict__ W_ffnn, const float* __restrict__ b_ffnn,
    float* __restrict__ hpart, unsigned* __restrict__ ub32, int N)
{
    __shared__ int hist[NBP];           // used by precount path only (4 KB)
    const int tid = threadIdx.x;

    if ((int)blockIdx.x >= jgrid) {
        // ================= precount path =================
        for (int i = tid; i < NBP; i += 256) hist[i] = 0;
        __syncthreads();
        const int e0 = ((int)blockIdx.x - jgrid) * PRE_E;
        const int eend = min(e0 + PRE_E, E);
        for (int e = e0 + tid; e < eend; e += 256) {
            atomicAdd(&hist[src[e] >> 7], 1);
            atomicAdd(&hist[dst[e] >> 7], 1);
        }
        __syncthreads();
        for (int i = tid; i < NBP; i += 256)
            if (hist[i] > 0) atomicAdd(&gtotal[i], hist[i]);
        return;
    }

    // ================= proj path (1 node/thread, scalar weights) ==========
    const int node = (int)blockIdx.x * 256 + tid;
    if (node >= N) return;

    const float4* frow = (const float4*)(feat + (size_t)node * 128);

    float acc[32];
#pragma unroll
    for (int c = 0; c < 32; ++c) acc[c] = b_in[c];          // uniform -> s_load

    // GEMM1: weight index depends only on loop counters -> wave-uniform
#pragma unroll 4
    for (int k4 = 0; k4 < 32; ++k4) {
        const float4 f = frow[k4];
#pragma unroll
        for (int kk = 0; kk < 4; ++kk) {
            const float fk = (kk == 0) ? f.x : (kk == 1) ? f.y : (kk == 2) ? f.z : f.w;
            const float* wr = W_in + (k4 * 4 + kk) * 32;
#pragma unroll
            for (int c = 0; c < 32; ++c)
                acc[c] = fmaf(fk, wr[c], acc[c]);
        }
    }

    // GEMM2: u = sigmoid(h @ W_nbr + b2); fully unrolled (static acc[k])
    {
        float u[32];
#pragma unroll
        for (int c = 0; c < 32; ++c) u[c] = b_nbr[c] + b_n1[c];
#pragma unroll
        for (int k = 0; k < 32; ++k) {
            const float hv = acc[k];
            const float* wr = W_nbr + k * 32;
#pragma unroll
            for (int c = 0; c < 32; ++c)
                u[c] = fmaf(hv, wr[c], u[c]);
        }
        // sigmoid -> bf16 (RNE) -> channel-split tables, packed u32 writes
#pragma unroll
        for (int j = 0; j < 16; ++j) {
            const int q = j >> 3, jj = j & 7;
            const int c = q * 16 + 2 * jj;
            float s0 = 1.0f / (1.0f + __expf(-u[c]));
            float s1 = 1.0f / (1.0f + __expf(-u[c + 1]));
            unsigned b0 = __float_as_uint(s0);
            b0 += 0x7FFFu + ((b0 >> 16) & 1u);
            unsigned b1 = __float_as_uint(s1);
            b1 += 0x7FFFu + ((b1 >> 16) & 1u);
            ub32[((size_t)q * N + node) * 8 + jj] = (b0 >> 16) | (b1 & 0xFFFF0000u);
        }
    }

    // hpart = h @ W_ffnn[0:32] + b_ffnn; fully unrolled
    {
        float g[32];
#pragma unroll
        for (int c = 0; c < 32; ++c) g[c] = b_ffnn[c];
#pragma unroll
        for (int k = 0; k < 32; ++k) {
            const float hv = acc[k];
            const float* wr = W_ffnn + k * 32;
#pragma unroll
            for (int c = 0; c < 32; ++c)
                g[c] = fmaf(hv, wr[c], g[c]);
        }
        float4* hr = (float4*)(hpart + (size_t)node * 32);
#pragma unroll
        for (int c4 = 0; c4 < 8; ++c4)
            hr[c4] = make_float4(g[c4 * 4 + 0], g[c4 * 4 + 1],
                                 g[c4 * 4 + 2], g[c4 * 4 + 3]);
    }
}

// ---------------------------------------------------------------------------
// Bucket-granular scatter (standalone; 38.9 KB LDS, 4 blocks/CU).
// Bucket low byte rides in code bits 24..31; recovered via cur containment.
// ---------------------------------------------------------------------------
__global__ __launch_bounds__(256) void bucket_scatter(
    const int* __restrict__ src, const int* __restrict__ dst,
    int* __restrict__ gcursor, unsigned* __restrict__ pairs_g,
    int E, int B)
{
    __shared__ unsigned s_code[SCAT_P];     // 30 KB
    __shared__ int s_cur[NBP];              // 4 KB (counts -> starts -> ends)
    __shared__ int s_gbL[NBP];              // 4 KB (also scan temp [0..3])

    const int tid = threadIdx.x;
    const int e0 = blockIdx.x * SCAT_E;
    const int eend = min(e0 + SCAT_E, E);
    const int np = 2 * (eend - e0);

    for (int i = tid; i < NBP; i += 256) s_cur[i] = 0;
    __syncthreads();

    int es[EPT], dr[EPT];
#pragma unroll
    for (int j = 0; j < EPT; ++j) {
        int e = e0 + tid + j * 256;
        bool ok = (e < eend);
        es[j] = ok ? src[e] : -1;
        dr[j] = ok ? dst[e] : -1;
    }
#pragma unroll
    for (int j = 0; j < EPT; ++j) {
        if (es[j] >= 0) {
            atomicAdd(&s_cur[es[j] >> 7], 1);
            atomicAdd(&s_cur[dr[j] >> 7], 1);
        }
    }
    __syncthreads();

    // in-place exclusive scan of cur (counts -> starts); shfl-based
    {
        const int lane = tid & 63;
        const int w = tid >> 6;
        int v0 = s_cur[4 * tid], v1 = s_cur[4 * tid + 1];
        int v2 = s_cur[4 * tid + 2], v3 = s_cur[4 * tid + 3];
        int tsum = v0 + v1 + v2 + v3;
        int x = tsum;
#pragma unroll
        for (int off = 1; off < 64; off <<= 1) {
            int y = __shfl_up(x, off, 64);
            x += (lane >= off) ? y : 0;
        }
        if (lane == 63) s_gbL[w] = x;       // wave totals (temp use)
        __syncthreads();
        int woff = 0;
#pragma unroll
        for (int k = 0; k < 4; ++k) woff += (k < w) ? s_gbL[k] : 0;
        int ebase = woff + x - tsum;
        __syncthreads();                    // all reads of cur done
        s_cur[4 * tid] = ebase;
        s_cur[4 * tid + 1] = ebase + v0;
        s_cur[4 * tid + 2] = ebase + v0 + v1;
        s_cur[4 * tid + 3] = ebase + v0 + v1 + v2;
    }
    __syncthreads();

    // rank + reorder into LDS; bucket low byte in code[31:24]
#pragma unroll
    for (int j = 0; j < EPT; ++j) {
        if (es[j] >= 0) {
            int s = es[j], d = dr[j];
            int bs = s >> 7, bd = d >> 7;
            unsigned cs = ((unsigned)(bs & 255) << 24) |
                          ((unsigned)(s & 127) << 17) | (unsigned)d;
            unsigned cd = ((unsigned)(bd & 255) << 24) |
                          ((unsigned)(d & 127) << 17) | (unsigned)s;
            int p1 = atomicAdd(&s_cur[bs], 1);
            s_code[p1] = cs;
            int p2 = atomicAdd(&s_cur[bd], 1);
            s_code[p2] = cd;
        }
    }
    __syncthreads();
    // cur[b] = segment END; start(b) = cur[b-1] (segments packed)

    for (int b = tid; b < B; b += 256) {
        int end = s_cur[b];
        int start = b ? s_cur[b - 1] : 0;
        int c = end - start;
        if (c > 0) {
            int gw = atomicAdd(&gcursor[b], c);
            s_gbL[b] = gw - start;
        }
    }
    __syncthreads();

    // coalesced run writes; recover bucket via low byte + containment
    for (int i = tid; i < np; i += 256) {
        unsigned code = s_code[i];
        int cc = (int)(code >> 24);
#pragma unroll
        for (int k = 0; k < 3; ++k) {
            int hi2 = s_cur[cc];
            int lo2 = cc ? s_cur[cc - 1] : 0;
            bool in = (i < hi2) && (i >= lo2);
            cc = in ? cc : cc + 256;
        }
        pairs_g[s_gbL[cc] + i] = code & 0x00FFFFFFu;
    }
}

// ---------------------------------------------------------------------------
// Per-bucket segment max in LDS. XCD-aware decode: q = xcd>=4 so each XCD's
// L2 caches only ITS 3.2MB u-table. 16-deep unrolled gathers per lane.
// ---------------------------------------------------------------------------
__global__ __launch_bounds__(256) void bucket_max(
    const unsigned* __restrict__ pairs_g, const int* __restrict__ gbase,
    const int* __restrict__ gtotal, const unsigned* __restrict__ ub32,
    float* __restrict__ agg, int N, int B)
{
    __shared__ unsigned aggL[BSZ * PAD];   // 8.7 KB
    __shared__ int degL[BSZ];              // 0.5 KB
    __shared__ unsigned tile[TS];          // 16 KB

    const int tid = threadIdx.x;
    const int bid = blockIdx.x;
    const int xcd = bid & 7;
    const int q = xcd >> 2;                          // channel half by XCD group
    const int b = (bid >> 3) * 4 + (xcd & 3);
    if (b >= B) return;
    const int v0 = b * BSZ;
    const unsigned* ut = ub32 + (size_t)q * N * 8;   // 8 u32 per node

    for (int i = tid; i < BSZ * PAD; i += 256) aggL[i] = 0u;
    for (int i = tid; i < BSZ; i += 256) degL[i] = 0;
    __syncthreads();

    const int start = gbase[b];
    const int cnt = gtotal[b];
    const int gg = tid >> 3;       // 32 groups of 8 lanes
    const int cl = tid & 7;

    for (int t0 = 0; t0 < cnt; t0 += TS) {
        const int tn = min(TS, cnt - t0);
        for (int i = tid; i < tn; i += 256) tile[i] = pairs_g[start + t0 + i];
        __syncthreads();

        const int kmax = (tn - gg + 31) >> 5;   // <=0 if gg >= tn
        const int pm = tn - 1;
        for (int kk = 0; kk < kmax; kk += 16) {
            unsigned cc[16], xx[16];
#pragma unroll
            for (int u = 0; u < 16; ++u)
                cc[u] = tile[min(gg + (kk + u) * 32, pm)];
#pragma unroll
            for (int u = 0; u < 16; ++u)
                xx[u] = ut[(size_t)(cc[u] & 0x1FFFF) * 8 + cl];
#pragma unroll
            for (int u = 0; u < 16; ++u) {
                atomicMax(&aggL[(cc[u] >> 17) * PAD + 2 * cl], (xx[u] & 0xFFFFu) << 16);
                atomicMax(&aggL[(cc[u] >> 17) * PAD + 2 * cl + 1], xx[u] & 0xFFFF0000u);
            }
            if (cl == 0) {
#pragma unroll
                for (int u = 0; u < 16; ++u)
                    if (gg + (kk + u) * 32 < tn) atomicAdd(&degL[cc[u] >> 17], 1);
            }
        }
        __syncthreads();
    }

    for (int i = tid; i < BSZ * CPG; i += 256) {
        int vl = i >> 4;
        int v = v0 + vl;
        if (v < N) {
            float val = (degL[vl] > 1) ? __uint_as_float(aggL[vl * PAD + (i & 15)]) : 0.f;
            agg[(size_t)v * DH + q * CPG + (i & 15)] = val;
        }
    }
}

// ---------------------------------------------------------------------------
// out = hpart + agg @ W_ffnn[32:64]; scalar (wave-uniform) weight loads,
// no LDS, fully unrolled.
// ---------------------------------------------------------------------------
__global__ __launch_bounds__(256) void fin(
    const float* __restrict__ hpart, const float* __restrict__ agg,
    const float* __restrict__ W_ffnn, float* __restrict__ out, int N)
{
    const int node = blockIdx.x * 256 + threadIdx.x;
    if (node >= N) return;

    const float4* hr = (const float4*)(hpart + (size_t)node * 32);
    const float4* ar = (const float4*)(agg + (size_t)node * 32);

    float acc[32], a[32];
#pragma unroll
    for (int c4 = 0; c4 < 8; ++c4) {
        float4 v = hr[c4];
        acc[c4 * 4 + 0] = v.x; acc[c4 * 4 + 1] = v.y;
        acc[c4 * 4 + 2] = v.z; acc[c4 * 4 + 3] = v.w;
        float4 w = ar[c4];
        a[c4 * 4 + 0] = w.x; a[c4 * 4 + 1] = w.y;
        a[c4 * 4 + 2] = w.z; a[c4 * 4 + 3] = w.w;
    }

    const float* W2h = W_ffnn + 1024;   // rows 32..63
#pragma unroll
    for (int k = 0; k < 32; ++k) {
        const float hv = a[k];
        const float* wr = W2h + k * 32;
#pragma unroll
        for (int c = 0; c < 32; ++c)
            acc[c] = fmaf(hv, wr[c], acc[c]);
    }

    float4* orow = (float4*)(out + (size_t)node * 32);
#pragma unroll
    for (int c4 = 0; c4 < 8; ++c4)
        orow[c4] = make_float4(acc[c4 * 4 + 0], acc[c4 * 4 + 1],
                               acc[c4 * 4 + 2], acc[c4 * 4 + 3]);
}

// ---------------------------------------------------------------------------
extern "C" void kernel_launch(void* const* d_in, const int* in_sizes, int n_in,
                              void* d_out, int out_size, void* d_ws, size_t ws_size,
                              hipStream_t stream)
{
    const float* feat   = (const float*)d_in[0];
    const int*   src    = (const int*)d_in[1];
    const int*   dst    = (const int*)d_in[2];
    const float* W_in   = (const float*)d_in[3];
    const float* b_in   = (const float*)d_in[4];
    const float* W_nbr  = (const float*)d_in[5];
    const float* b_nbr  = (const float*)d_in[6];
    const float* b_n1   = (const float*)d_in[7];
    const float* W_ffnn = (const float*)d_in[8];
    const float* b_ffnn = (const float*)d_in[9];
    float* out = (float*)d_out;

    const int N = in_sizes[0] / 128;   // 100000 (N <= 131072 required by packing)
    const int E = in_sizes[1];
    const int B = (N + BSZ - 1) / BSZ; // 782 buckets (<= NBP)

    // u (bf16, channel-split, 6.4MB) aliases d_out (12.8MB): written by the
    // proj path, consumed by bucket_max, then fin overwrites out.
    unsigned* ub32 = (unsigned*)out;
    float* hpart   = (float*)d_ws;                    // N*32 f32
    float* agg     = hpart + (size_t)N * DH;          // N*32 f32
    int*   gtotal  = (int*)(agg + (size_t)N * DH);    // NBP
    int*   gbase   = gtotal + NBP;                    // NBP
    int*   gcursor = gbase + NBP;                     // NBP
    unsigned* pairs_g = (unsigned*)(gcursor + NBP);   // 2E u32

    const int egrid = (E + SCAT_E - 1) / SCAT_E;      // 261
    const int pgrid = (E + PRE_E - 1) / PRE_E;        // 123
    const int jgrid = (N + 255) / 256;                // 391 proj blocks (first)
    const int npb = (N + 255) / 256;                  // 391

    hipMemsetAsync(gtotal, 0, NBP * sizeof(int), stream);
    precount_proj<<<jgrid + pgrid, 256, 0, stream>>>(
        src, dst, gtotal, E, jgrid,
        feat, W_in, b_in, W_nbr, b_nbr, b_n1, W_ffnn, b_ffnn,
        hpart, ub32, N);
    scan_buckets<<<1, 256, 0, stream>>>(gtotal, gbase, gcursor);
    bucket_scatter<<<egrid, 256, 0, stream>>>(src, dst, gcursor, pairs_g, E, B);
    bucket_max<<<((B + 3) / 4) * 8, 256, 0, stream>>>(
        pairs_g, gbase, gtotal, ub32, agg, N, B);
    fin<<<npb, 256, 0, stream>>>(hpart, agg, W_ffnn, out, N);
}

// Round 15
// 107.895 us; speedup vs baseline: 1.5165x; 1.2274x over previous
//
#include <hip/hip_runtime.h>
#include <hip/hip_bf16.h>

#define DH 32
#define BSZ 128      // nodes per bucket (v_local = 7 bits)
#define NBP 1024     // padded bucket count (N <= 131072 => B <= 1024)
#define SCAT_E 3840  // edges per scatter block
#define SCAT_P (2 * SCAT_E)
#define EPT 15       // edges per thread in scatter (SCAT_E/256)
#define PRE_E 8192   // edges per precount block
#define CPG 16       // channels per sub-block in bucket_max
#define TS 4096      // pair codes per LDS tile in bucket_max
#define PAD 17       // aggL words per node (16 channels + 1 pad)
#define TPW 4        // 16-node tiles per wave in proj

typedef short bf16x8 __attribute__((ext_vector_type(8)));
typedef float f32x4 __attribute__((ext_vector_type(4)));

__device__ __forceinline__ unsigned short f2bf(float x) {
    unsigned b = __float_as_uint(x);
    b += 0x7FFFu + ((b >> 16) & 1u);     // RNE
    return (unsigned short)(b >> 16);
}

// ---------------------------------------------------------------------------
// Exclusive scan of gtotal[0..NBP) -> gbase; gcursor = gbase. One block.
// ---------------------------------------------------------------------------
__global__ __launch_bounds__(256) void scan_buckets(
    const int* __restrict__ gtotal, int* __restrict__ gbase,
    int* __restrict__ gcursor)
{
    __shared__ int ss[256];
    const int t = threadIdx.x;
    int v0 = gtotal[4 * t], v1 = gtotal[4 * t + 1];
    int v2 = gtotal[4 * t + 2], v3 = gtotal[4 * t + 3];
    int tsum = v0 + v1 + v2 + v3;
    ss[t] = tsum;
    __syncthreads();
    for (int off = 1; off < 256; off <<= 1) {
        int y = (t >= off) ? ss[t - off] : 0;
        __syncthreads();
        ss[t] += y;
        __syncthreads();
    }
    int e = ss[t] - tsum;
    gbase[4 * t] = e;                    gcursor[4 * t] = e;
    gbase[4 * t + 1] = e + v0;           gcursor[4 * t + 1] = e + v0;
    gbase[4 * t + 2] = e + v0 + v1;      gcursor[4 * t + 2] = e + v0 + v1;
    gbase[4 * t + 3] = e + v0 + v1 + v2; gcursor[4 * t + 3] = e + v0 + v1 + v2;
}

// ---------------------------------------------------------------------------
// FUSED: blocks [0, jgrid) = MFMA node projection (wave = 16-node tiles;
// weights live in VGPRs as B-fragments); blocks [jgrid, ...) = precount.
//   h = feat @ W_in + b_in                (MFMA, 4 K-steps x 2 col-tiles)
//   u = sigmoid(h @ W_nbr + b2)           (MFMA, K=32, via 1KB LDS bounce)
//   hpart = h @ W_ffnn[0:32] + b_ffnn     (MFMA)
// Fragment layouts (m89-verified): A: row=l&15, k=(l>>4)*8+j; B: col=l&15,
// k=(l>>4)*8+j; C/D: col=l&15, row=(l>>4)*4+reg.
// ---------------------------------------------------------------------------
__global__ __launch_bounds__(256) void precount_proj(
    const int* __restrict__ src, const int* __restrict__ dst,
    int* __restrict__ gtotal, int E, int jgrid,
    const float* __restrict__ feat,
    const float* __restrict__ W_in, const float* __restrict__ b_in,
    const float* __restrict__ W_nbr, const float* __restrict__ b_nbr,
    const float* __restrict__ b_n1,
    const float* __restrict__ W_ffnn, const float* __restrict__ b_ffnn,
    float* __restrict__ hpart, unsigned short* __restrict__ ub16,
    int N, int ntiles)
{
    __shared__ union {
        int hist[NBP];                       // precount path (4 KB)
        unsigned short htile[4][16 * 32];    // proj path: per-wave h bounce
    } sm;
    const int tid = threadIdx.x;

    if ((int)blockIdx.x >= jgrid) {
        // ================= precount path =================
        for (int i = tid; i < NBP; i += 256) sm.hist[i] = 0;
        __syncthreads();
        const int e0 = ((int)blockIdx.x - jgrid) * PRE_E;
        const int eend = min(e0 + PRE_E, E);
        for (int e = e0 + tid; e < eend; e += 256) {
            atomicAdd(&sm.hist[src[e] >> 7], 1);
            atomicAdd(&sm.hist[dst[e] >> 7], 1);
        }
        __syncthreads();
        for (int i = tid; i < NBP; i += 256)
            if (sm.hist[i] > 0) atomicAdd(&gtotal[i], sm.hist[i]);
        return;
    }

    // ================= proj path (MFMA) =================
    const int wid = tid >> 6, lane = tid & 63;
    const int r16 = lane & 15, kg = lane >> 4;

    // B fragments (weights -> bf16, once per wave)
    bf16x8 B1[4][2], B2[2], Bf[2];
#pragma unroll
    for (int ks = 0; ks < 4; ++ks)
#pragma unroll
        for (int ct = 0; ct < 2; ++ct)
#pragma unroll
            for (int j = 0; j < 8; ++j)
                B1[ks][ct][j] = (short)f2bf(
                    W_in[(ks * 32 + kg * 8 + j) * 32 + ct * 16 + r16]);
#pragma unroll
    for (int ct = 0; ct < 2; ++ct)
#pragma unroll
        for (int j = 0; j < 8; ++j) {
            B2[ct][j] = (short)f2bf(W_nbr[(kg * 8 + j) * 32 + ct * 16 + r16]);
            Bf[ct][j] = (short)f2bf(W_ffnn[(kg * 8 + j) * 32 + ct * 16 + r16]);
        }

    const float b1a = b_in[r16],            b1b = b_in[16 + r16];
    const float b2a = b_nbr[r16] + b_n1[r16];
    const float b2b = b_nbr[16 + r16] + b_n1[16 + r16];
    const float bfa = b_ffnn[r16],          bfb = b_ffnn[16 + r16];

    unsigned short* hl = &sm.htile[wid][0];
    const int w = (int)blockIdx.x * 4 + wid;

    for (int i = 0; i < TPW; ++i) {
        const int t = w * TPW + i;
        if (t >= ntiles) break;              // wave-uniform
        const int tbase = t * 16;
        const int nA = tbase + r16;
        const bool okA = (nA < N);
        const float* fr = feat + (size_t)(okA ? nA : 0) * 128;

        // A fragments: 8 consecutive k per lane (two float4 loads + cvt)
        bf16x8 A[4];
#pragma unroll
        for (int ks = 0; ks < 4; ++ks) {
            float4 p0 = make_float4(0.f, 0.f, 0.f, 0.f);
            float4 p1 = make_float4(0.f, 0.f, 0.f, 0.f);
            if (okA) {
                p0 = *(const float4*)(fr + ks * 32 + kg * 8);
                p1 = *(const float4*)(fr + ks * 32 + kg * 8 + 4);
            }
            A[ks][0] = (short)f2bf(p0.x); A[ks][1] = (short)f2bf(p0.y);
            A[ks][2] = (short)f2bf(p0.z); A[ks][3] = (short)f2bf(p0.w);
            A[ks][4] = (short)f2bf(p1.x); A[ks][5] = (short)f2bf(p1.y);
            A[ks][6] = (short)f2bf(p1.z); A[ks][7] = (short)f2bf(p1.w);
        }

        // GEMM1: h-tile = feat-tile @ W_in + b_in
        f32x4 acc0 = {b1a, b1a, b1a, b1a};
        f32x4 acc1 = {b1b, b1b, b1b, b1b};
#pragma unroll
        for (int ks = 0; ks < 4; ++ks) {
            acc0 = __builtin_amdgcn_mfma_f32_16x16x32_bf16(A[ks], B1[ks][0], acc0, 0, 0, 0);
            acc1 = __builtin_amdgcn_mfma_f32_16x16x32_bf16(A[ks], B1[ks][1], acc1, 0, 0, 0);
        }

        // bounce h (bf16) through wave-private LDS: C-layout -> A-layout
#pragma unroll
        for (int r = 0; r < 4; ++r) {
            hl[(kg * 4 + r) * 32 + r16]      = f2bf(acc0[r]);
            hl[(kg * 4 + r) * 32 + 16 + r16] = f2bf(acc1[r]);
        }
        asm volatile("s_waitcnt lgkmcnt(0)" ::: "memory");
        bf16x8 A2 = *reinterpret_cast<const bf16x8*>(&hl[r16 * 32 + kg * 8]);

        // GEMM2 (u) and hpart, K=32 single step each
        f32x4 u0 = {b2a, b2a, b2a, b2a};
        f32x4 u1 = {b2b, b2b, b2b, b2b};
        u0 = __builtin_amdgcn_mfma_f32_16x16x32_bf16(A2, B2[0], u0, 0, 0, 0);
        u1 = __builtin_amdgcn_mfma_f32_16x16x32_bf16(A2, B2[1], u1, 0, 0, 0);
        f32x4 g0 = {bfa, bfa, bfa, bfa};
        f32x4 g1 = {bfb, bfb, bfb, bfb};
        g0 = __builtin_amdgcn_mfma_f32_16x16x32_bf16(A2, Bf[0], g0, 0, 0, 0);
        g1 = __builtin_amdgcn_mfma_f32_16x16x32_bf16(A2, Bf[1], g1, 0, 0, 0);

        // stores: lane covers nodes tbase + kg*4 + r, channel r16 (+16)
#pragma unroll
        for (int r = 0; r < 4; ++r) {
            const int n2 = tbase + kg * 4 + r;
            if (n2 < N) {
                float s0 = 1.0f / (1.0f + __expf(-u0[r]));
                float s1 = 1.0f / (1.0f + __expf(-u1[r]));
                ub16[(size_t)n2 * 16 + r16]              = f2bf(s0);  // half 0
                ub16[((size_t)N + n2) * 16 + r16]        = f2bf(s1);  // half 1
                hpart[(size_t)n2 * 32 + r16]      = g0[r];
                hpart[(size_t)n2 * 32 + 16 + r16] = g1[r];
            }
        }
    }
}

// ---------------------------------------------------------------------------
// Bucket-granular scatter (standalone; 38.9 KB LDS, 4 blocks/CU).
// Bucket low byte rides in code bits 24..31; recovered via cur containment.
// ---------------------------------------------------------------------------
__global__ __launch_bounds__(256) void bucket_scatter(
    const int* __restrict__ src, const int* __restrict__ dst,
    int* __restrict__ gcursor, unsigned* __restrict__ pairs_g,
    int E, int B)
{
    __shared__ unsigned s_code[SCAT_P];     // 30 KB
    __shared__ int s_cur[NBP];              // 4 KB (counts -> starts -> ends)
    __shared__ int s_gbL[NBP];              // 4 KB (also scan temp [0..3])

    const int tid = threadIdx.x;
    const int e0 = blockIdx.x * SCAT_E;
    const int eend = min(e0 + SCAT_E, E);
    const int np = 2 * (eend - e0);

    for (int i = tid; i < NBP; i += 256) s_cur[i] = 0;
    __syncthreads();

    int es[EPT], dr[EPT];
#pragma unroll
    for (int j = 0; j < EPT; ++j) {
        int e = e0 + tid + j * 256;
        bool ok = (e < eend);
        es[j] = ok ? src[e] : -1;
        dr[j] = ok ? dst[e] : -1;
    }
#pragma unroll
    for (int j = 0; j < EPT; ++j) {
        if (es[j] >= 0) {
            atomicAdd(&s_cur[es[j] >> 7], 1);
            atomicAdd(&s_cur[dr[j] >> 7], 1);
        }
    }
    __syncthreads();

    // in-place exclusive scan of cur (counts -> starts); shfl-based
    {
        const int lane = tid & 63;
        const int w = tid >> 6;
        int v0 = s_cur[4 * tid], v1 = s_cur[4 * tid + 1];
        int v2 = s_cur[4 * tid + 2], v3 = s_cur[4 * tid + 3];
        int tsum = v0 + v1 + v2 + v3;
        int x = tsum;
#pragma unroll
        for (int off = 1; off < 64; off <<= 1) {
            int y = __shfl_up(x, off, 64);
            x += (lane >= off) ? y : 0;
        }
        if (lane == 63) s_gbL[w] = x;       // wave totals (temp use)
        __syncthreads();
        int woff = 0;
#pragma unroll
        for (int k = 0; k < 4; ++k) woff += (k < w) ? s_gbL[k] : 0;
        int ebase = woff + x - tsum;
        __syncthreads();                    // all reads of cur done
        s_cur[4 * tid] = ebase;
        s_cur[4 * tid + 1] = ebase + v0;
        s_cur[4 * tid + 2] = ebase + v0 + v1;
        s_cur[4 * tid + 3] = ebase + v0 + v1 + v2;
    }
    __syncthreads();

    // rank + reorder into LDS; bucket low byte in code[31:24]
#pragma unroll
    for (int j = 0; j < EPT; ++j) {
        if (es[j] >= 0) {
            int s = es[j], d = dr[j];
            int bs = s >> 7, bd = d >> 7;
            unsigned cs = ((unsigned)(bs & 255) << 24) |
                          ((unsigned)(s & 127) << 17) | (unsigned)d;
            unsigned cd = ((unsigned)(bd & 255) << 24) |
                          ((unsigned)(d & 127) << 17) | (unsigned)s;
            int p1 = atomicAdd(&s_cur[bs], 1);
            s_code[p1] = cs;
            int p2 = atomicAdd(&s_cur[bd], 1);
            s_code[p2] = cd;
        }
    }
    __syncthreads();
    // cur[b] = segment END; start(b) = cur[b-1] (segments packed)

    for (int b = tid; b < B; b += 256) {
        int end = s_cur[b];
        int start = b ? s_cur[b - 1] : 0;
        int c = end - start;
        if (c > 0) {
            int gw = atomicAdd(&gcursor[b], c);
            s_gbL[b] = gw - start;
        }
    }
    __syncthreads();

    // coalesced run writes; recover bucket via low byte + containment
    for (int i = tid; i < np; i += 256) {
        unsigned code = s_code[i];
        int cc = (int)(code >> 24);
#pragma unroll
        for (int k = 0; k < 3; ++k) {
            int hi2 = s_cur[cc];
            int lo2 = cc ? s_cur[cc - 1] : 0;
            bool in = (i < hi2) && (i >= lo2);
            cc = in ? cc : cc + 256;
        }
        pairs_g[s_gbL[cc] + i] = code & 0x00FFFFFFu;
    }
}

// ---------------------------------------------------------------------------
// Per-bucket segment max in LDS. XCD-aware decode: q = xcd>=4 so each XCD's
// L2 caches only ITS 3.2MB u-table. 16-deep unrolled gathers per lane.
// ---------------------------------------------------------------------------
__global__ __launch_bounds__(256) void bucket_max(
    const unsigned* __restrict__ pairs_g, const int* __restrict__ gbase,
    const int* __restrict__ gtotal, const unsigned* __restrict__ ub32,
    float* __restrict__ agg, int N, int B)
{
    __shared__ unsigned aggL[BSZ * PAD];   // 8.7 KB
    __shared__ int degL[BSZ];              // 0.5 KB
    __shared__ unsigned tile[TS];          // 16 KB

    const int tid = threadIdx.x;
    const int bid = blockIdx.x;
    const int xcd = bid & 7;
    const int q = xcd >> 2;                          // channel half by XCD group
    const int b = (bid >> 3) * 4 + (xcd & 3);
    if (b >= B) return;
    const int v0 = b * BSZ;
    const unsigned* ut = ub32 + (size_t)q * N * 8;   // 8 u32 per node

    for (int i = tid; i < BSZ * PAD; i += 256) aggL[i] = 0u;
    for (int i = tid; i < BSZ; i += 256) degL[i] = 0;
    __syncthreads();

    const int start = gbase[b];
    const int cnt = gtotal[b];
    const int gg = tid >> 3;       // 32 groups of 8 lanes
    const int cl = tid & 7;

    for (int t0 = 0; t0 < cnt; t0 += TS) {
        const int tn = min(TS, cnt - t0);
        for (int i = tid; i < tn; i += 256) tile[i] = pairs_g[start + t0 + i];
        __syncthreads();

        const int kmax = (tn - gg + 31) >> 5;   // <=0 if gg >= tn
        const int pm = tn - 1;
        for (int kk = 0; kk < kmax; kk += 16) {
            unsigned cc[16], xx[16];
#pragma unroll
            for (int u = 0; u < 16; ++u)
                cc[u] = tile[min(gg + (kk + u) * 32, pm)];
#pragma unroll
            for (int u = 0; u < 16; ++u)
                xx[u] = ut[(size_t)(cc[u] & 0x1FFFF) * 8 + cl];
#pragma unroll
            for (int u = 0; u < 16; ++u) {
                atomicMax(&aggL[(cc[u] >> 17) * PAD + 2 * cl], (xx[u] & 0xFFFFu) << 16);
                atomicMax(&aggL[(cc[u] >> 17) * PAD + 2 * cl + 1], xx[u] & 0xFFFF0000u);
            }
            if (cl == 0) {
#pragma unroll
                for (int u = 0; u < 16; ++u)
                    if (gg + (kk + u) * 32 < tn) atomicAdd(&degL[cc[u] >> 17], 1);
            }
        }
        __syncthreads();
    }

    for (int i = tid; i < BSZ * CPG; i += 256) {
        int vl = i >> 4;
        int v = v0 + vl;
        if (v < N) {
            float val = (degL[vl] > 1) ? __uint_as_float(aggL[vl * PAD + (i & 15)]) : 0.f;
            agg[(size_t)v * DH + q * CPG + (i & 15)] = val;
        }
    }
}

// ---------------------------------------------------------------------------
// out = hpart + agg @ W_ffnn[32:64]; wave-uniform weight loads, no LDS.
// ---------------------------------------------------------------------------
__global__ __launch_bounds__(256) void fin(
    const float* __restrict__ hpart, const float* __restrict__ agg,
    const float* __restrict__ W_ffnn, float* __restrict__ out, int N)
{
    const int node = blockIdx.x * 256 + threadIdx.x;
    if (node >= N) return;

    const float4* hr = (const float4*)(hpart + (size_t)node * 32);
    const float4* ar = (const float4*)(agg + (size_t)node * 32);

    float acc[32], a[32];
#pragma unroll
    for (int c4 = 0; c4 < 8; ++c4) {
        float4 v = hr[c4];
        acc[c4 * 4 + 0] = v.x; acc[c4 * 4 + 1] = v.y;
        acc[c4 * 4 + 2] = v.z; acc[c4 * 4 + 3] = v.w;
        float4 w = ar[c4];
        a[c4 * 4 + 0] = w.x; a[c4 * 4 + 1] = w.y;
        a[c4 * 4 + 2] = w.z; a[c4 * 4 + 3] = w.w;
    }

    const float* W2h = W_ffnn + 1024;   // rows 32..63
#pragma unroll
    for (int k = 0; k < 32; ++k) {
        const float hv = a[k];
        const float* wr = W2h + k * 32;
#pragma unroll
        for (int c = 0; c < 32; ++c)
            acc[c] = fmaf(hv, wr[c], acc[c]);
    }

    float4* orow = (float4*)(out + (size_t)node * 32);
#pragma unroll
    for (int c4 = 0; c4 < 8; ++c4)
        orow[c4] = make_float4(acc[c4 * 4 + 0], acc[c4 * 4 + 1],
                               acc[c4 * 4 + 2], acc[c4 * 4 + 3]);
}

// ---------------------------------------------------------------------------
extern "C" void kernel_launch(void* const* d_in, const int* in_sizes, int n_in,
                              void* d_out, int out_size, void* d_ws, size_t ws_size,
                              hipStream_t stream)
{
    const float* feat   = (const float*)d_in[0];
    const int*   src    = (const int*)d_in[1];
    const int*   dst    = (const int*)d_in[2];
    const float* W_in   = (const float*)d_in[3];
    const float* b_in   = (const float*)d_in[4];
    const float* W_nbr  = (const float*)d_in[5];
    const float* b_nbr  = (const float*)d_in[6];
    const float* b_n1   = (const float*)d_in[7];
    const float* W_ffnn = (const float*)d_in[8];
    const float* b_ffnn = (const float*)d_in[9];
    float* out = (float*)d_out;

    const int N = in_sizes[0] / 128;   // 100000 (N <= 131072 required by packing)
    const int E = in_sizes[1];
    const int B = (N + BSZ - 1) / BSZ; // 782 buckets (<= NBP)
    const int ntiles = (N + 15) / 16;  // 6250 16-node tiles

    // u (bf16, channel-split, 6.4MB) aliases d_out (12.8MB): written by the
    // proj path, consumed by bucket_max, then fin overwrites out.
    unsigned short* ub16 = (unsigned short*)out;
    float* hpart   = (float*)d_ws;                    // N*32 f32
    float* agg     = hpart + (size_t)N * DH;          // N*32 f32
    int*   gtotal  = (int*)(agg + (size_t)N * DH);    // NBP
    int*   gbase   = gtotal + NBP;                    // NBP
    int*   gcursor = gbase + NBP;                     // NBP
    unsigned* pairs_g = (unsigned*)(gcursor + NBP);   // 2E u32

    const int egrid = (E + SCAT_E - 1) / SCAT_E;      // 261
    const int pgrid = (E + PRE_E - 1) / PRE_E;        // 123
    const int jgrid = (ntiles + 4 * TPW - 1) / (4 * TPW);  // 391 proj blocks
    const int npb = (N + 255) / 256;                  // 391

    hipMemsetAsync(gtotal, 0, NBP * sizeof(int), stream);
    precount_proj<<<jgrid + pgrid, 256, 0, stream>>>(
        src, dst, gtotal, E, jgrid,
        feat, W_in, b_in, W_nbr, b_nbr, b_n1, W_ffnn, b_ffnn,
        hpart, ub16, N, ntiles);
    scan_buckets<<<1, 256, 0, stream>>>(gtotal, gbase, gcursor);
    bucket_scatter<<<egrid, 256, 0, stream>>>(src, dst, gcursor, pairs_g, E, B);
    bucket_max<<<((B + 3) / 4) * 8, 256, 0, stream>>>(
        pairs_g, gbase, gtotal, (const unsigned*)ub16, agg, N, B);
    fin<<<npb, 256, 0, stream>>>(hpart, agg, W_ffnn, out, N);
}